// Round 11
// baseline (559.278 us; speedup 1.0000x reference)
//
#include <hip/hip_runtime.h>
#include <stdint.h>

using u16 = unsigned short;
typedef __bf16 bf16x8 __attribute__((ext_vector_type(8)));
typedef float f32x4 __attribute__((ext_vector_type(4)));

__device__ __forceinline__ u16 f2bf(float f) {
  union { float f; uint32_t u; } v; v.f = f;
  uint32_t r = v.u + 0x7fffu + ((v.u >> 16) & 1u);
  return (u16)(r >> 16);
}
__device__ __forceinline__ float bf2f(u16 h) {
  union { uint32_t u; float f; } v; v.u = ((uint32_t)h) << 16;
  return v.f;
}
__device__ __forceinline__ bf16x8 ldb8(const u16* p) {
  return *reinterpret_cast<const bf16x8*>(p);
}
__device__ __forceinline__ void gload_lds16(const void* g, void* l) {
  __builtin_amdgcn_global_load_lds(
      (const __attribute__((address_space(1))) void*)g,
      (__attribute__((address_space(3))) void*)l, 16, 0, 0);
}

// ---------------- elementwise convert f32 -> bf16 ----------------
__global__ __launch_bounds__(256) void convert_f32_bf16(
    const float* __restrict__ in, u16* __restrict__ out, int n4) {
  int idx = (blockIdx.x * 256 + threadIdx.x);
  if (idx >= n4) return;
  float4 v = *(const float4*)(in + (size_t)idx * 4);
  ushort4 o;
  o.x = f2bf(v.x); o.y = f2bf(v.y); o.z = f2bf(v.z); o.w = f2bf(v.w);
  *(ushort4*)(out + (size_t)idx * 4) = o;
}

// ---------------- transpose + convert: W (K x N f32) -> Wt (N x K bf16) ----
__global__ void transpose_convert(const float* __restrict__ W,
                                  u16* __restrict__ Wt, int K, int N) {
  __shared__ u16 tile[32][33];
  int n0 = blockIdx.x * 32, k0 = blockIdx.y * 32;
  int tx = threadIdx.x, ty = threadIdx.y;  // (32, 8)
#pragma unroll
  for (int i = 0; i < 32; i += 8)
    tile[ty + i][tx] = f2bf(W[(size_t)(k0 + ty + i) * N + n0 + tx]);
  __syncthreads();
#pragma unroll
  for (int i = 0; i < 32; i += 8)
    Wt[(size_t)(n0 + ty + i) * K + k0 + tx] = tile[tx][ty + i];
}

// ---------------- GEMM 128x128: C = A * Bt^T ------------------------------
__global__ __launch_bounds__(256) void gemm_bt(
    const u16* __restrict__ A, const u16* __restrict__ Bt,
    u16* __restrict__ C, int M, int N, int K) {
  __shared__ __align__(16) u16 As[128 * 32];
  __shared__ __align__(16) u16 Bs[128 * 32];
  const int tid = threadIdx.x;
  const int w = tid >> 6, lane = tid & 63;
  const int wr = w >> 1, wc = w & 1;
  const int r16 = lane & 15, g = lane >> 4;
  const int m0 = blockIdx.y * 128, n0 = blockIdx.x * 128;
  const int ldrow = lane >> 2;
  const int ldk = (lane & 3) * 8;

  f32x4 acc[4][4] = {};

  for (int kt = 0; kt < K; kt += 32) {
#pragma unroll
    for (int i = 0; i < 2; ++i) {
      int chunk = w * 2 + i;
      int row = chunk * 16 + ldrow;
      gload_lds16(A + (size_t)(m0 + row) * K + kt + ldk, &As[chunk * 512]);
      gload_lds16(Bt + (size_t)(n0 + row) * K + kt + ldk, &Bs[chunk * 512]);
    }
    __syncthreads();
    bf16x8 a[4], b[4];
#pragma unroll
    for (int mt = 0; mt < 4; ++mt)
      a[mt] = ldb8(&As[(wr * 64 + mt * 16 + r16) * 32 + g * 8]);
#pragma unroll
    for (int nt = 0; nt < 4; ++nt)
      b[nt] = ldb8(&Bs[(wc * 64 + nt * 16 + r16) * 32 + g * 8]);
#pragma unroll
    for (int mt = 0; mt < 4; ++mt)
#pragma unroll
      for (int nt = 0; nt < 4; ++nt)
        acc[mt][nt] = __builtin_amdgcn_mfma_f32_16x16x32_bf16(
            a[mt], b[nt], acc[mt][nt], 0, 0, 0);
    __syncthreads();
  }
#pragma unroll
  for (int mt = 0; mt < 4; ++mt)
#pragma unroll
    for (int nt = 0; nt < 4; ++nt)
#pragma unroll
      for (int r = 0; r < 4; ++r) {
        int row = m0 + wr * 64 + mt * 16 + g * 4 + r;
        int col = n0 + wc * 64 + nt * 16 + r16;
        C[(size_t)row * N + col] = f2bf(acc[mt][nt][r]);
      }
}

// ---------------- GEMM 64x128: for small-N GEMMs (2x the blocks) ----------
__global__ __launch_bounds__(256) void gemm_bt64(
    const u16* __restrict__ A, const u16* __restrict__ Bt,
    u16* __restrict__ C, int M, int N, int K) {
  __shared__ __align__(16) u16 As[64 * 32];
  __shared__ __align__(16) u16 Bs[128 * 32];
  const int tid = threadIdx.x;
  const int w = tid >> 6, lane = tid & 63;
  const int wr = w >> 1, wc = w & 1;
  const int r16 = lane & 15, g = lane >> 4;
  const int m0 = blockIdx.y * 64, n0 = blockIdx.x * 128;
  const int ldrow = lane >> 2;
  const int ldk = (lane & 3) * 8;

  f32x4 acc[2][4] = {};

  for (int kt = 0; kt < K; kt += 32) {
#pragma unroll
    for (int i = 0; i < 3; ++i) {
      int chunk = w * 3 + i;  // 0..11: 0-3 -> A, 4-11 -> B
      if (chunk < 4) {
        int row = chunk * 16 + ldrow;
        gload_lds16(A + (size_t)(m0 + row) * K + kt + ldk, &As[chunk * 512]);
      } else {
        int cb = chunk - 4;
        int row = cb * 16 + ldrow;
        gload_lds16(Bt + (size_t)(n0 + row) * K + kt + ldk, &Bs[cb * 512]);
      }
    }
    __syncthreads();
    bf16x8 a[2], b[4];
#pragma unroll
    for (int mt = 0; mt < 2; ++mt)
      a[mt] = ldb8(&As[(wr * 32 + mt * 16 + r16) * 32 + g * 8]);
#pragma unroll
    for (int nt = 0; nt < 4; ++nt)
      b[nt] = ldb8(&Bs[(wc * 64 + nt * 16 + r16) * 32 + g * 8]);
#pragma unroll
    for (int mt = 0; mt < 2; ++mt)
#pragma unroll
      for (int nt = 0; nt < 4; ++nt)
        acc[mt][nt] = __builtin_amdgcn_mfma_f32_16x16x32_bf16(
            a[mt], b[nt], acc[mt][nt], 0, 0, 0);
    __syncthreads();
  }
#pragma unroll
  for (int mt = 0; mt < 2; ++mt)
#pragma unroll
    for (int nt = 0; nt < 4; ++nt)
#pragma unroll
      for (int r = 0; r < 4; ++r) {
        int row = m0 + wr * 32 + mt * 16 + g * 4 + r;
        int col = n0 + wc * 64 + nt * 16 + r16;
        C[(size_t)row * N + col] = f2bf(acc[mt][nt][r]);
      }
}

// ---------------- RoPE + split + V-transpose (exact R2) -------------------
__global__ __launch_bounds__(256) void rope_kernel(
    const u16* __restrict__ qkv, const float* __restrict__ cosb,
    const float* __restrict__ sinb, u16* __restrict__ qb,
    u16* __restrict__ kb, u16* __restrict__ vt) {
  int idx = blockIdx.x * 256 + threadIdx.x;
  int d = idx & 63;
  int h = (idx >> 6) & 15;
  int s = idx >> 10;
  size_t base = (size_t)s * 3072;
  float q = bf2f(qkv[base + h * 64 + d]);
  float k = bf2f(qkv[base + (16 + h) * 64 + d]);
  float v = bf2f(qkv[base + (32 + h) * 64 + d]);
  float c = cosb[s * 64 + d], sn = sinb[s * 64 + d];
  int dp = d < 32 ? d + 32 : d - 32;
  float sgn = d < 32 ? -1.f : 1.f;
  float qr = bf2f(qkv[base + h * 64 + dp]);
  float kr = bf2f(qkv[base + (16 + h) * 64 + dp]);
  float qo = q * c + sgn * qr * sn;
  float ko = k * c + sgn * kr * sn;
  size_t o = ((size_t)h * 2048 + s) * 64 + d;
  qb[o] = f2bf(qo * 0.125f);  // fold score scale 1/sqrt(64)
  kb[o] = f2bf(ko);
  vt[((size_t)h * 64 + d) * 2048 + s] = f2bf(v);
}

// ---------------- flash attention: 64 q-rows, 8 waves, 2 blocks/CU --------
// R9 geometry (64 q-rows/block, 512 blocks, same bijective XCD swizzle ->
// K/V traffic & L3-friendly FETCH ~166MB) with R10's concurrency (16
// waves/CU): 512-thread blocks, 8 waves, each owning a 256-wide KV slice.
// Math byte-identical (4 q-subtiles, R2 online softmax); combine is 8-way.
__global__ __launch_bounds__(512, 4) void attn_kernel(
    const u16* __restrict__ qb, const u16* __restrict__ kb,
    const u16* __restrict__ vt, const float* __restrict__ bias,
    u16* __restrict__ attnb) {
  const int bid = blockIdx.x;
  const int swz = (bid & 7) * 64 + (bid >> 3);  // XCD r -> heads {2r,2r+1}
  const int h = swz >> 5;
  const int qt = swz & 31;  // 64-row q-tile
  const int tid = threadIdx.x;
  const int w = tid >> 6;        // 0..7
  const int lane = tid & 63;
  const int r16 = lane & 15, g = lane >> 4;

  __shared__ __align__(16) u16 P_lds[8][16 * 32];
  __shared__ float acc_s[8][16][64];
  __shared__ float m_s[8][16], l_s[8][16];

  bf16x8 qf0[4], qf1[4];
#pragma unroll
  for (int st = 0; st < 4; ++st) {
    const u16* qrow =
        qb + ((size_t)h * 2048 + qt * 64 + st * 16 + r16) * 64;
    qf0[st] = ldb8(qrow + g * 8);
    qf1[st] = ldb8(qrow + 32 + g * 8);
  }

  f32x4 acc[4][4] = {};
  float m[4][4], lsum[4][4];
#pragma unroll
  for (int st = 0; st < 4; ++st)
#pragma unroll
    for (int r = 0; r < 4; ++r) { m[st][r] = -1e30f; lsum[st][r] = 0.f; }

  const float* bbase = bias + ((size_t)h * 2048 + qt * 64) * 2048;

  const int kv0 = w * 256, kv1 = kv0 + 256;
  for (int kt = kv0; kt < kv1; kt += 32) {
    // K/V chunk loaded ONCE, reused by all 4 q-subtiles
    bf16x8 ka[2], kc[2];
#pragma unroll
    for (int c = 0; c < 2; ++c) {
      const u16* krow = kb + ((size_t)h * 2048 + kt + c * 16 + r16) * 64;
      ka[c] = ldb8(krow + g * 8);
      kc[c] = ldb8(krow + 32 + g * 8);
    }
    bf16x8 vf[4];
#pragma unroll
    for (int nt = 0; nt < 4; ++nt)
      vf[nt] =
          ldb8(vt + ((size_t)h * 64 + nt * 16 + r16) * 2048 + kt + g * 8);

#pragma unroll
    for (int st = 0; st < 4; ++st) {
      float bv[2][4];
#pragma unroll
      for (int c = 0; c < 2; ++c)
#pragma unroll
        for (int r = 0; r < 4; ++r)
          bv[c][r] = bbase[(size_t)(st * 16 + g * 4 + r) * 2048 + kt +
                           c * 16 + r16];

      f32x4 sc[2];
#pragma unroll
      for (int c = 0; c < 2; ++c) {
        f32x4 z = {0.f, 0.f, 0.f, 0.f};
        f32x4 t =
            __builtin_amdgcn_mfma_f32_16x16x32_bf16(qf0[st], ka[c], z, 0, 0, 0);
        sc[c] =
            __builtin_amdgcn_mfma_f32_16x16x32_bf16(qf1[st], kc[c], t, 0, 0, 0);
      }
#pragma unroll
      for (int c = 0; c < 2; ++c)
#pragma unroll
        for (int r = 0; r < 4; ++r)
          sc[c][r] += bv[c][r];

      float mnew[4], rs[4];
#pragma unroll
      for (int r = 0; r < 4; ++r) {
        float t = fmaxf(sc[0][r], sc[1][r]);
        t = fmaxf(t, __shfl_xor(t, 1));
        t = fmaxf(t, __shfl_xor(t, 2));
        t = fmaxf(t, __shfl_xor(t, 4));
        t = fmaxf(t, __shfl_xor(t, 8));
        mnew[r] = fmaxf(m[st][r], t);
      }
#pragma unroll
      for (int r = 0; r < 4; ++r) {
        float p0 = __expf(sc[0][r] - mnew[r]);
        float p1 = __expf(sc[1][r] - mnew[r]);
        sc[0][r] = p0; sc[1][r] = p1;
        float t = p0 + p1;
        t += __shfl_xor(t, 1);
        t += __shfl_xor(t, 2);
        t += __shfl_xor(t, 4);
        t += __shfl_xor(t, 8);
        rs[r] = t;
        float alpha = __expf(m[st][r] - mnew[r]);
        lsum[st][r] = lsum[st][r] * alpha + rs[r];
        m[st][r] = mnew[r];
#pragma unroll
        for (int nt = 0; nt < 4; ++nt) acc[st][nt][r] *= alpha;
      }
#pragma unroll
      for (int c = 0; c < 2; ++c)
#pragma unroll
        for (int r = 0; r < 4; ++r)
          P_lds[w][(g * 4 + r) * 32 + c * 16 + r16] = f2bf(sc[c][r]);
      bf16x8 pf = ldb8(&P_lds[w][r16 * 32 + g * 8]);
#pragma unroll
      for (int nt = 0; nt < 4; ++nt)
        acc[st][nt] = __builtin_amdgcn_mfma_f32_16x16x32_bf16(
            pf, vf[nt], acc[st][nt], 0, 0, 0);
    }
  }

  // combine per subtile: 8-way reduce; 512 threads x 2 outputs
#pragma unroll
  for (int st = 0; st < 4; ++st) {
    __syncthreads();  // previous subtile's combine reads done
#pragma unroll
    for (int nt = 0; nt < 4; ++nt)
#pragma unroll
      for (int r = 0; r < 4; ++r)
        acc_s[w][g * 4 + r][nt * 16 + r16] = acc[st][nt][r];
    if (r16 == 0) {
#pragma unroll
      for (int r = 0; r < 4; ++r) {
        m_s[w][g * 4 + r] = m[st][r];
        l_s[w][g * 4 + r] = lsum[st][r];
      }
    }
    __syncthreads();

    const int row = tid >> 5;         // 0..15
    const int col2 = (tid & 31) * 2;  // 0..62 step 2
    float mm = m_s[0][row];
#pragma unroll
    for (int w8 = 1; w8 < 8; ++w8) mm = fmaxf(mm, m_s[w8][row]);
    float sw[8];
    float ltot = 0.f;
#pragma unroll
    for (int w8 = 0; w8 < 8; ++w8) {
      sw[w8] = __expf(m_s[w8][row] - mm);
      ltot += l_s[w8][row] * sw[w8];
    }
    float inv = 1.f / ltot;
    float v0 = 0.f, v1 = 0.f;
#pragma unroll
    for (int w8 = 0; w8 < 8; ++w8) {
      v0 += acc_s[w8][row][col2] * sw[w8];
      v1 += acc_s[w8][row][col2 + 1] * sw[w8];
    }
    ushort2 ov;
    ov.x = f2bf(v0 * inv);
    ov.y = f2bf(v1 * inv);
    *(ushort2*)(attnb + (size_t)(qt * 64 + st * 16 + row) * 1024 + h * 64 +
                col2) = ov;
  }
}

// ---------------- residual add + RMSNorm ----------------------------------
__global__ __launch_bounds__(256) void addnorm_kernel(
    const float* __restrict__ resid, const u16* __restrict__ delta,
    float* __restrict__ outf, u16* __restrict__ outb) {
  int row = blockIdx.x, tid = threadIdx.x;
  size_t base = (size_t)row * 1024 + tid * 4;
  float4 rv = *(const float4*)(resid + base);
  ushort4 dv = *(const ushort4*)(delta + base);
  float x0 = rv.x + bf2f(dv.x);
  float x1 = rv.y + bf2f(dv.y);
  float x2 = rv.z + bf2f(dv.z);
  float x3 = rv.w + bf2f(dv.w);
  float ss = x0 * x0 + x1 * x1 + x2 * x2 + x3 * x3;
#pragma unroll
  for (int sh = 32; sh >= 1; sh >>= 1) ss += __shfl_xor(ss, sh);
  __shared__ float red[4];
  if ((tid & 63) == 0) red[tid >> 6] = ss;
  __syncthreads();
  float tot = red[0] + red[1] + red[2] + red[3];
  float rstd = rsqrtf(tot * (1.0f / 1024.0f) + 1e-5f);
  float4 ov;
  ov.x = x0 * rstd; ov.y = x1 * rstd; ov.z = x2 * rstd; ov.w = x3 * rstd;
  *(float4*)(outf + base) = ov;
  if (outb) {
    ushort4 ob;
    ob.x = f2bf(ov.x); ob.y = f2bf(ov.y); ob.z = f2bf(ov.z); ob.w = f2bf(ov.w);
    *(ushort4*)(outb + base) = ob;
  }
}

// ---------------- SwiGLU ---------------------------------------------------
__global__ __launch_bounds__(256) void swiglu_kernel(
    const u16* __restrict__ gu, u16* __restrict__ hb) {
  int s = blockIdx.x, tid = threadIdx.x;
  const u16* grow = gu + (size_t)s * 5632;
  u16* hrow = hb + (size_t)s * 2816;
  for (int j = tid * 4; j < 2816; j += 1024) {
    ushort4 gv = *(const ushort4*)(grow + j);
    ushort4 uv = *(const ushort4*)(grow + 2816 + j);
    float g0 = bf2f(gv.x), g1 = bf2f(gv.y), g2 = bf2f(gv.z), g3 = bf2f(gv.w);
    float u0 = bf2f(uv.x), u1 = bf2f(uv.y), u2 = bf2f(uv.z), u3 = bf2f(uv.w);
    ushort4 ho;
    ho.x = f2bf(g0 / (1.f + __expf(-g0)) * u0);
    ho.y = f2bf(g1 / (1.f + __expf(-g1)) * u1);
    ho.z = f2bf(g2 / (1.f + __expf(-g2)) * u2);
    ho.w = f2bf(g3 / (1.f + __expf(-g3)) * u3);
    *(ushort4*)(hrow + j) = ho;
  }
}

extern "C" void kernel_launch(void* const* d_in, const int* in_sizes, int n_in,
                              void* d_out, int out_size, void* d_ws,
                              size_t ws_size, hipStream_t stream) {
  (void)in_sizes; (void)n_in; (void)out_size; (void)ws_size;
  const float* cosb  = (const float*)d_in[0];
  const float* sinb  = (const float*)d_in[1];
  const float* hidden = (const float*)d_in[2];
  const float* bias  = (const float*)d_in[3];
  const float* w_qkv = (const float*)d_in[4];
  const float* w_o   = (const float*)d_in[5];
  const float* w_gu  = (const float*)d_in[6];
  const float* w_down = (const float*)d_in[7];
  float* out = (float*)d_out;

  char* p = (char*)d_ws;
  auto alloc = [&](size_t bytes) {
    void* r = (void*)p;
    p += (bytes + 255) & ~(size_t)255;
    return r;
  };
  u16* wqkv_t = (u16*)alloc((size_t)3072 * 1024 * 2);
  u16* wo_t   = (u16*)alloc((size_t)1024 * 1024 * 2);
  u16* wgu_t  = (u16*)alloc((size_t)5632 * 1024 * 2);
  u16* wd_t   = (u16*)alloc((size_t)1024 * 2816 * 2);
  u16* xb     = (u16*)alloc((size_t)2048 * 1024 * 2);
  u16* qkvb   = (u16*)alloc((size_t)2048 * 3072 * 2);
  u16* qb     = (u16*)alloc((size_t)16 * 2048 * 64 * 2);
  u16* kb     = (u16*)alloc((size_t)16 * 2048 * 64 * 2);
  u16* vt     = (u16*)alloc((size_t)16 * 2048 * 64 * 2);
  u16* attnb  = (u16*)alloc((size_t)2048 * 1024 * 2);
  u16* ob     = (u16*)alloc((size_t)2048 * 1024 * 2);
  float* x1f  = (float*)alloc((size_t)2048 * 1024 * 4);
  u16* x1b    = (u16*)alloc((size_t)2048 * 1024 * 2);
  u16* gub    = (u16*)alloc((size_t)2048 * 5632 * 2);
  u16* hb     = (u16*)alloc((size_t)2048 * 2816 * 2);
  u16* mlpb   = (u16*)alloc((size_t)2048 * 1024 * 2);

  dim3 tb(32, 8);
  convert_f32_bf16<<<2048, 256, 0, stream>>>(hidden, xb, 2048 * 1024 / 4);
  transpose_convert<<<dim3(3072 / 32, 1024 / 32), tb, 0, stream>>>(w_qkv, wqkv_t, 1024, 3072);
  transpose_convert<<<dim3(1024 / 32, 1024 / 32), tb, 0, stream>>>(w_o, wo_t, 1024, 1024);
  transpose_convert<<<dim3(5632 / 32, 1024 / 32), tb, 0, stream>>>(w_gu, wgu_t, 1024, 5632);
  transpose_convert<<<dim3(1024 / 32, 2816 / 32), tb, 0, stream>>>(w_down, wd_t, 2816, 1024);

  gemm_bt<<<dim3(3072 / 128, 2048 / 128), 256, 0, stream>>>(xb, wqkv_t, qkvb, 2048, 3072, 1024);
  rope_kernel<<<(2048 * 16 * 64) / 256, 256, 0, stream>>>(qkvb, cosb, sinb, qb, kb, vt);
  attn_kernel<<<512, 512, 0, stream>>>(qb, kb, vt, bias, attnb);
  gemm_bt64<<<dim3(1024 / 128, 2048 / 64), 256, 0, stream>>>(attnb, wo_t, ob, 2048, 1024, 1024);
  addnorm_kernel<<<2048, 256, 0, stream>>>(hidden, ob, x1f, x1b);
  gemm_bt<<<dim3(5632 / 128, 2048 / 128), 256, 0, stream>>>(x1b, wgu_t, gub, 2048, 5632, 1024);
  swiglu_kernel<<<2048, 256, 0, stream>>>(gub, hb);
  gemm_bt64<<<dim3(1024 / 128, 2048 / 64), 256, 0, stream>>>(hb, wd_t, mlpb, 2048, 1024, 2816);
  addnorm_kernel<<<2048, 256, 0, stream>>>(x1f, mlpb, out, nullptr);
}

// Round 12
// 321.970 us; speedup vs baseline: 1.7370x; 1.7370x over previous
//
#include <hip/hip_runtime.h>
#include <stdint.h>

using u16 = unsigned short;
typedef __bf16 bf16x8 __attribute__((ext_vector_type(8)));
typedef float f32x4 __attribute__((ext_vector_type(4)));

__device__ __forceinline__ u16 f2bf(float f) {
  union { float f; uint32_t u; } v; v.f = f;
  uint32_t r = v.u + 0x7fffu + ((v.u >> 16) & 1u);
  return (u16)(r >> 16);
}
__device__ __forceinline__ float bf2f(u16 h) {
  union { uint32_t u; float f; } v; v.u = ((uint32_t)h) << 16;
  return v.f;
}
__device__ __forceinline__ bf16x8 ldb8(const u16* p) {
  return *reinterpret_cast<const bf16x8*>(p);
}
__device__ __forceinline__ void gload_lds16(const void* g, void* l) {
  __builtin_amdgcn_global_load_lds(
      (const __attribute__((address_space(1))) void*)g,
      (__attribute__((address_space(3))) void*)l, 16, 0, 0);
}

// ---------------- elementwise convert f32 -> bf16 ----------------
__global__ __launch_bounds__(256) void convert_f32_bf16(
    const float* __restrict__ in, u16* __restrict__ out, int n4) {
  int idx = (blockIdx.x * 256 + threadIdx.x);
  if (idx >= n4) return;
  float4 v = *(const float4*)(in + (size_t)idx * 4);
  ushort4 o;
  o.x = f2bf(v.x); o.y = f2bf(v.y); o.z = f2bf(v.z); o.w = f2bf(v.w);
  *(ushort4*)(out + (size_t)idx * 4) = o;
}

// ---------------- transpose + convert: W (K x N f32) -> Wt (N x K bf16) ----
__global__ void transpose_convert(const float* __restrict__ W,
                                  u16* __restrict__ Wt, int K, int N) {
  __shared__ u16 tile[32][33];
  int n0 = blockIdx.x * 32, k0 = blockIdx.y * 32;
  int tx = threadIdx.x, ty = threadIdx.y;  // (32, 8)
#pragma unroll
  for (int i = 0; i < 32; i += 8)
    tile[ty + i][tx] = f2bf(W[(size_t)(k0 + ty + i) * N + n0 + tx]);
  __syncthreads();
#pragma unroll
  for (int i = 0; i < 32; i += 8)
    Wt[(size_t)(n0 + ty + i) * K + k0 + tx] = tile[tx][ty + i];
}

// ---------------- GEMM 128x128: C = A * Bt^T (XCD-swizzled) ---------------
// Grid block count must be divisible by 8 (all call sites satisfy this).
__global__ __launch_bounds__(256) void gemm_bt(
    const u16* __restrict__ A, const u16* __restrict__ Bt,
    u16* __restrict__ C, int M, int N, int K) {
  __shared__ __align__(16) u16 As[128 * 32];
  __shared__ __align__(16) u16 Bs[128 * 32];
  const int tid = threadIdx.x;
  const int w = tid >> 6, lane = tid & 63;
  const int wr = w >> 1, wc = w & 1;
  const int r16 = lane & 15, g = lane >> 4;
  const int nwg = gridDim.x * gridDim.y;
  const int idx = blockIdx.y * gridDim.x + blockIdx.x;
  const int swz = (idx & 7) * (nwg >> 3) + (idx >> 3);  // bijective, nwg%8==0
  const int m0 = (swz / gridDim.x) * 128, n0 = (swz % gridDim.x) * 128;
  const int ldrow = lane >> 2;
  const int ldk = (lane & 3) * 8;

  f32x4 acc[4][4] = {};

  for (int kt = 0; kt < K; kt += 32) {
#pragma unroll
    for (int i = 0; i < 2; ++i) {
      int chunk = w * 2 + i;
      int row = chunk * 16 + ldrow;
      gload_lds16(A + (size_t)(m0 + row) * K + kt + ldk, &As[chunk * 512]);
      gload_lds16(Bt + (size_t)(n0 + row) * K + kt + ldk, &Bs[chunk * 512]);
    }
    __syncthreads();
    bf16x8 a[4], b[4];
#pragma unroll
    for (int mt = 0; mt < 4; ++mt)
      a[mt] = ldb8(&As[(wr * 64 + mt * 16 + r16) * 32 + g * 8]);
#pragma unroll
    for (int nt = 0; nt < 4; ++nt)
      b[nt] = ldb8(&Bs[(wc * 64 + nt * 16 + r16) * 32 + g * 8]);
#pragma unroll
    for (int mt = 0; mt < 4; ++mt)
#pragma unroll
      for (int nt = 0; nt < 4; ++nt)
        acc[mt][nt] = __builtin_amdgcn_mfma_f32_16x16x32_bf16(
            a[mt], b[nt], acc[mt][nt], 0, 0, 0);
    __syncthreads();
  }
#pragma unroll
  for (int mt = 0; mt < 4; ++mt)
#pragma unroll
    for (int nt = 0; nt < 4; ++nt)
#pragma unroll
      for (int r = 0; r < 4; ++r) {
        int row = m0 + wr * 64 + mt * 16 + g * 4 + r;
        int col = n0 + wc * 64 + nt * 16 + r16;
        C[(size_t)row * N + col] = f2bf(acc[mt][nt][r]);
      }
}

// ---------------- GEMM 64x128 (XCD-swizzled) ------------------------------
__global__ __launch_bounds__(256) void gemm_bt64(
    const u16* __restrict__ A, const u16* __restrict__ Bt,
    u16* __restrict__ C, int M, int N, int K) {
  __shared__ __align__(16) u16 As[64 * 32];
  __shared__ __align__(16) u16 Bs[128 * 32];
  const int tid = threadIdx.x;
  const int w = tid >> 6, lane = tid & 63;
  const int wr = w >> 1, wc = w & 1;
  const int r16 = lane & 15, g = lane >> 4;
  const int nwg = gridDim.x * gridDim.y;
  const int idx = blockIdx.y * gridDim.x + blockIdx.x;
  const int swz = (idx & 7) * (nwg >> 3) + (idx >> 3);  // bijective, nwg%8==0
  const int m0 = (swz / gridDim.x) * 64, n0 = (swz % gridDim.x) * 128;
  const int ldrow = lane >> 2;
  const int ldk = (lane & 3) * 8;

  f32x4 acc[2][4] = {};

  for (int kt = 0; kt < K; kt += 32) {
#pragma unroll
    for (int i = 0; i < 3; ++i) {
      int chunk = w * 3 + i;  // 0..11: 0-3 -> A, 4-11 -> B
      if (chunk < 4) {
        int row = chunk * 16 + ldrow;
        gload_lds16(A + (size_t)(m0 + row) * K + kt + ldk, &As[chunk * 512]);
      } else {
        int cb = chunk - 4;
        int row = cb * 16 + ldrow;
        gload_lds16(Bt + (size_t)(n0 + row) * K + kt + ldk, &Bs[cb * 512]);
      }
    }
    __syncthreads();
    bf16x8 a[2], b[4];
#pragma unroll
    for (int mt = 0; mt < 2; ++mt)
      a[mt] = ldb8(&As[(wr * 32 + mt * 16 + r16) * 32 + g * 8]);
#pragma unroll
    for (int nt = 0; nt < 4; ++nt)
      b[nt] = ldb8(&Bs[(wc * 64 + nt * 16 + r16) * 32 + g * 8]);
#pragma unroll
    for (int mt = 0; mt < 2; ++mt)
#pragma unroll
      for (int nt = 0; nt < 4; ++nt)
        acc[mt][nt] = __builtin_amdgcn_mfma_f32_16x16x32_bf16(
            a[mt], b[nt], acc[mt][nt], 0, 0, 0);
    __syncthreads();
  }
#pragma unroll
  for (int mt = 0; mt < 2; ++mt)
#pragma unroll
    for (int nt = 0; nt < 4; ++nt)
#pragma unroll
      for (int r = 0; r < 4; ++r) {
        int row = m0 + wr * 32 + mt * 16 + g * 4 + r;
        int col = n0 + wc * 64 + nt * 16 + r16;
        C[(size_t)row * N + col] = f2bf(acc[mt][nt][r]);
      }
}

// ---------------- RoPE + split + coalesced V-transpose --------------------
// Block = (head, 32-seq tile), 256 threads. Math per (s,h,d) identical to
// the verified R2 rope. V is staged in LDS and written to vt with
// 64B-contiguous row segments (was 2B scattered writes at stride 2048).
__global__ __launch_bounds__(256) void rope_kernel(
    const u16* __restrict__ qkv, const float* __restrict__ cosb,
    const float* __restrict__ sinb, u16* __restrict__ qb,
    u16* __restrict__ kb, u16* __restrict__ vt) {
  const int h = blockIdx.y;
  const int s0 = blockIdx.x * 32;
  const int t = threadIdx.x;
  const int d = t & 63;
  const int sgrp = t >> 6;  // 0..3

  __shared__ u16 vs[64][33];  // [d][s_local], pad to break bank alignment

#pragma unroll
  for (int it = 0; it < 8; ++it) {
    const int sl = it * 4 + sgrp;
    const int s = s0 + sl;
    const size_t base = (size_t)s * 3072;
    float q = bf2f(qkv[base + h * 64 + d]);
    float k = bf2f(qkv[base + (16 + h) * 64 + d]);
    float v = bf2f(qkv[base + (32 + h) * 64 + d]);
    float c = cosb[s * 64 + d], sn = sinb[s * 64 + d];
    int dp = d < 32 ? d + 32 : d - 32;
    float sgn = d < 32 ? -1.f : 1.f;
    float qr = bf2f(qkv[base + h * 64 + dp]);
    float kr = bf2f(qkv[base + (16 + h) * 64 + dp]);
    float qo = q * c + sgn * qr * sn;
    float ko = k * c + sgn * kr * sn;
    size_t o = ((size_t)h * 2048 + s) * 64 + d;
    qb[o] = f2bf(qo * 0.125f);  // fold score scale 1/sqrt(64)
    kb[o] = f2bf(ko);
    vs[d][sl] = f2bf(v);
  }
  __syncthreads();

  // write vt[(h*64+d)*2048 + s0 .. +32): 4 threads x 8 u16 per d-row
  const int d2 = t >> 2;        // 0..63
  const int sc8 = (t & 3) * 8;  // 0,8,16,24
  ushort4 o0, o1;
  o0.x = vs[d2][sc8 + 0]; o0.y = vs[d2][sc8 + 1];
  o0.z = vs[d2][sc8 + 2]; o0.w = vs[d2][sc8 + 3];
  o1.x = vs[d2][sc8 + 4]; o1.y = vs[d2][sc8 + 5];
  o1.z = vs[d2][sc8 + 6]; o1.w = vs[d2][sc8 + 7];
  u16* dst = vt + ((size_t)h * 64 + d2) * 2048 + s0 + sc8;
  *(ushort4*)(dst) = o0;
  *(ushort4*)(dst + 4) = o1;
}

// ---------------- flash attention (R9-exact) ------------------------------
// Block = (head, 64 q-rows), 4 waves; wave w owns KV [w*512, +512).
// Bijective XCD swizzle: XCD r covers heads {2r, 2r+1}.
__global__ __launch_bounds__(256, 2) void attn_kernel(
    const u16* __restrict__ qb, const u16* __restrict__ kb,
    const u16* __restrict__ vt, const float* __restrict__ bias,
    u16* __restrict__ attnb) {
  const int bid = blockIdx.x;
  const int swz = (bid & 7) * 64 + (bid >> 3);
  const int h = swz >> 5;
  const int qt = swz & 31;
  const int tid = threadIdx.x;
  const int w = tid >> 6;
  const int lane = tid & 63;
  const int r16 = lane & 15, g = lane >> 4;

  __shared__ __align__(16) u16 P_lds[4][16 * 32];
  __shared__ float acc_s[4][16][64];
  __shared__ float m_s[4][16], l_s[4][16];

  bf16x8 qf0[4], qf1[4];
#pragma unroll
  for (int st = 0; st < 4; ++st) {
    const u16* qrow =
        qb + ((size_t)h * 2048 + qt * 64 + st * 16 + r16) * 64;
    qf0[st] = ldb8(qrow + g * 8);
    qf1[st] = ldb8(qrow + 32 + g * 8);
  }

  f32x4 acc[4][4] = {};
  float m[4][4], lsum[4][4];
#pragma unroll
  for (int st = 0; st < 4; ++st)
#pragma unroll
    for (int r = 0; r < 4; ++r) { m[st][r] = -1e30f; lsum[st][r] = 0.f; }

  const float* bbase = bias + ((size_t)h * 2048 + qt * 64) * 2048;

  const int kv0 = w * 512, kv1 = kv0 + 512;
  for (int kt = kv0; kt < kv1; kt += 32) {
    bf16x8 ka[2], kc[2];
#pragma unroll
    for (int c = 0; c < 2; ++c) {
      const u16* krow = kb + ((size_t)h * 2048 + kt + c * 16 + r16) * 64;
      ka[c] = ldb8(krow + g * 8);
      kc[c] = ldb8(krow + 32 + g * 8);
    }
    bf16x8 vf[4];
#pragma unroll
    for (int nt = 0; nt < 4; ++nt)
      vf[nt] =
          ldb8(vt + ((size_t)h * 64 + nt * 16 + r16) * 2048 + kt + g * 8);

#pragma unroll
    for (int st = 0; st < 4; ++st) {
      float bv[2][4];
#pragma unroll
      for (int c = 0; c < 2; ++c)
#pragma unroll
        for (int r = 0; r < 4; ++r)
          bv[c][r] = bbase[(size_t)(st * 16 + g * 4 + r) * 2048 + kt +
                           c * 16 + r16];

      f32x4 sc[2];
#pragma unroll
      for (int c = 0; c < 2; ++c) {
        f32x4 z = {0.f, 0.f, 0.f, 0.f};
        f32x4 t =
            __builtin_amdgcn_mfma_f32_16x16x32_bf16(qf0[st], ka[c], z, 0, 0, 0);
        sc[c] =
            __builtin_amdgcn_mfma_f32_16x16x32_bf16(qf1[st], kc[c], t, 0, 0, 0);
      }
#pragma unroll
      for (int c = 0; c < 2; ++c)
#pragma unroll
        for (int r = 0; r < 4; ++r)
          sc[c][r] += bv[c][r];

      float mnew[4], rs[4];
#pragma unroll
      for (int r = 0; r < 4; ++r) {
        float t = fmaxf(sc[0][r], sc[1][r]);
        t = fmaxf(t, __shfl_xor(t, 1));
        t = fmaxf(t, __shfl_xor(t, 2));
        t = fmaxf(t, __shfl_xor(t, 4));
        t = fmaxf(t, __shfl_xor(t, 8));
        mnew[r] = fmaxf(m[st][r], t);
      }
#pragma unroll
      for (int r = 0; r < 4; ++r) {
        float p0 = __expf(sc[0][r] - mnew[r]);
        float p1 = __expf(sc[1][r] - mnew[r]);
        sc[0][r] = p0; sc[1][r] = p1;
        float t = p0 + p1;
        t += __shfl_xor(t, 1);
        t += __shfl_xor(t, 2);
        t += __shfl_xor(t, 4);
        t += __shfl_xor(t, 8);
        rs[r] = t;
        float alpha = __expf(m[st][r] - mnew[r]);
        lsum[st][r] = lsum[st][r] * alpha + rs[r];
        m[st][r] = mnew[r];
#pragma unroll
        for (int nt = 0; nt < 4; ++nt) acc[st][nt][r] *= alpha;
      }
#pragma unroll
      for (int c = 0; c < 2; ++c)
#pragma unroll
        for (int r = 0; r < 4; ++r)
          P_lds[w][(g * 4 + r) * 32 + c * 16 + r16] = f2bf(sc[c][r]);
      bf16x8 pf = ldb8(&P_lds[w][r16 * 32 + g * 8]);
#pragma unroll
      for (int nt = 0; nt < 4; ++nt)
        acc[st][nt] = __builtin_amdgcn_mfma_f32_16x16x32_bf16(
            pf, vf[nt], acc[st][nt], 0, 0, 0);
    }
  }

  // combine per subtile (LDS buffers reused; barriers separate subtiles)
#pragma unroll
  for (int st = 0; st < 4; ++st) {
    __syncthreads();  // previous subtile's combine reads done
#pragma unroll
    for (int nt = 0; nt < 4; ++nt)
#pragma unroll
      for (int r = 0; r < 4; ++r)
        acc_s[w][g * 4 + r][nt * 16 + r16] = acc[st][nt][r];
    if (r16 == 0) {
#pragma unroll
      for (int r = 0; r < 4; ++r) {
        m_s[w][g * 4 + r] = m[st][r];
        l_s[w][g * 4 + r] = lsum[st][r];
      }
    }
    __syncthreads();

    const int row = tid >> 4;
    const int col4 = (tid & 15) * 4;
    float m0v = m_s[0][row], m1v = m_s[1][row], m2v = m_s[2][row],
          m3v = m_s[3][row];
    float mm = fmaxf(fmaxf(m0v, m1v), fmaxf(m2v, m3v));
    float s0 = __expf(m0v - mm), s1 = __expf(m1v - mm);
    float s2 = __expf(m2v - mm), s3 = __expf(m3v - mm);
    float ltot = l_s[0][row] * s0 + l_s[1][row] * s1 + l_s[2][row] * s2 +
                 l_s[3][row] * s3;
    float inv = 1.f / ltot;
    ushort4 ov;
    u16* outp =
        attnb + (size_t)(qt * 64 + st * 16 + row) * 1024 + h * 64 + col4;
#pragma unroll
    for (int j = 0; j < 4; ++j) {
      float v = acc_s[0][row][col4 + j] * s0 + acc_s[1][row][col4 + j] * s1 +
                acc_s[2][row][col4 + j] * s2 + acc_s[3][row][col4 + j] * s3;
      ((u16*)&ov)[j] = f2bf(v * inv);
    }
    *(ushort4*)outp = ov;
  }
}

// ---------------- residual add + RMSNorm ----------------------------------
__global__ __launch_bounds__(256) void addnorm_kernel(
    const float* __restrict__ resid, const u16* __restrict__ delta,
    float* __restrict__ outf, u16* __restrict__ outb) {
  int row = blockIdx.x, tid = threadIdx.x;
  size_t base = (size_t)row * 1024 + tid * 4;
  float4 rv = *(const float4*)(resid + base);
  ushort4 dv = *(const ushort4*)(delta + base);
  float x0 = rv.x + bf2f(dv.x);
  float x1 = rv.y + bf2f(dv.y);
  float x2 = rv.z + bf2f(dv.z);
  float x3 = rv.w + bf2f(dv.w);
  float ss = x0 * x0 + x1 * x1 + x2 * x2 + x3 * x3;
#pragma unroll
  for (int sh = 32; sh >= 1; sh >>= 1) ss += __shfl_xor(ss, sh);
  __shared__ float red[4];
  if ((tid & 63) == 0) red[tid >> 6] = ss;
  __syncthreads();
  float tot = red[0] + red[1] + red[2] + red[3];
  float rstd = rsqrtf(tot * (1.0f / 1024.0f) + 1e-5f);
  float4 ov;
  ov.x = x0 * rstd; ov.y = x1 * rstd; ov.z = x2 * rstd; ov.w = x3 * rstd;
  *(float4*)(outf + base) = ov;
  if (outb) {
    ushort4 ob;
    ob.x = f2bf(ov.x); ob.y = f2bf(ov.y); ob.z = f2bf(ov.z); ob.w = f2bf(ov.w);
    *(ushort4*)(outb + base) = ob;
  }
}

// ---------------- SwiGLU ---------------------------------------------------
__global__ __launch_bounds__(256) void swiglu_kernel(
    const u16* __restrict__ gu, u16* __restrict__ hb) {
  int s = blockIdx.x, tid = threadIdx.x;
  const u16* grow = gu + (size_t)s * 5632;
  u16* hrow = hb + (size_t)s * 2816;
  for (int j = tid * 4; j < 2816; j += 1024) {
    ushort4 gv = *(const ushort4*)(grow + j);
    ushort4 uv = *(const ushort4*)(grow + 2816 + j);
    float g0 = bf2f(gv.x), g1 = bf2f(gv.y), g2 = bf2f(gv.z), g3 = bf2f(gv.w);
    float u0 = bf2f(uv.x), u1 = bf2f(uv.y), u2 = bf2f(uv.z), u3 = bf2f(uv.w);
    ushort4 ho;
    ho.x = f2bf(g0 / (1.f + __expf(-g0)) * u0);
    ho.y = f2bf(g1 / (1.f + __expf(-g1)) * u1);
    ho.z = f2bf(g2 / (1.f + __expf(-g2)) * u2);
    ho.w = f2bf(g3 / (1.f + __expf(-g3)) * u3);
    *(ushort4*)(hrow + j) = ho;
  }
}

extern "C" void kernel_launch(void* const* d_in, const int* in_sizes, int n_in,
                              void* d_out, int out_size, void* d_ws,
                              size_t ws_size, hipStream_t stream) {
  (void)in_sizes; (void)n_in; (void)out_size; (void)ws_size;
  const float* cosb  = (const float*)d_in[0];
  const float* sinb  = (const float*)d_in[1];
  const float* hidden = (const float*)d_in[2];
  const float* bias  = (const float*)d_in[3];
  const float* w_qkv = (const float*)d_in[4];
  const float* w_o   = (const float*)d_in[5];
  const float* w_gu  = (const float*)d_in[6];
  const float* w_down = (const float*)d_in[7];
  float* out = (float*)d_out;

  char* p = (char*)d_ws;
  auto alloc = [&](size_t bytes) {
    void* r = (void*)p;
    p += (bytes + 255) & ~(size_t)255;
    return r;
  };
  u16* wqkv_t = (u16*)alloc((size_t)3072 * 1024 * 2);
  u16* wo_t   = (u16*)alloc((size_t)1024 * 1024 * 2);
  u16* wgu_t  = (u16*)alloc((size_t)5632 * 1024 * 2);
  u16* wd_t   = (u16*)alloc((size_t)1024 * 2816 * 2);
  u16* xb     = (u16*)alloc((size_t)2048 * 1024 * 2);
  u16* qkvb   = (u16*)alloc((size_t)2048 * 3072 * 2);
  u16* qb     = (u16*)alloc((size_t)16 * 2048 * 64 * 2);
  u16* kb     = (u16*)alloc((size_t)16 * 2048 * 64 * 2);
  u16* vt     = (u16*)alloc((size_t)16 * 2048 * 64 * 2);
  u16* attnb  = (u16*)alloc((size_t)2048 * 1024 * 2);
  u16* ob     = (u16*)alloc((size_t)2048 * 1024 * 2);
  float* x1f  = (float*)alloc((size_t)2048 * 1024 * 4);
  u16* x1b    = (u16*)alloc((size_t)2048 * 1024 * 2);
  u16* gub    = (u16*)alloc((size_t)2048 * 5632 * 2);
  u16* hb     = (u16*)alloc((size_t)2048 * 2816 * 2);
  u16* mlpb   = (u16*)alloc((size_t)2048 * 1024 * 2);

  dim3 tb(32, 8);
  convert_f32_bf16<<<2048, 256, 0, stream>>>(hidden, xb, 2048 * 1024 / 4);
  transpose_convert<<<dim3(3072 / 32, 1024 / 32), tb, 0, stream>>>(w_qkv, wqkv_t, 1024, 3072);
  transpose_convert<<<dim3(1024 / 32, 1024 / 32), tb, 0, stream>>>(w_o, wo_t, 1024, 1024);
  transpose_convert<<<dim3(5632 / 32, 1024 / 32), tb, 0, stream>>>(w_gu, wgu_t, 1024, 5632);
  transpose_convert<<<dim3(1024 / 32, 2816 / 32), tb, 0, stream>>>(w_down, wd_t, 2816, 1024);

  gemm_bt<<<dim3(3072 / 128, 2048 / 128), 256, 0, stream>>>(xb, wqkv_t, qkvb, 2048, 3072, 1024);
  rope_kernel<<<dim3(64, 16), 256, 0, stream>>>(qkvb, cosb, sinb, qb, kb, vt);
  attn_kernel<<<512, 256, 0, stream>>>(qb, kb, vt, bias, attnb);
  gemm_bt64<<<dim3(1024 / 128, 2048 / 64), 256, 0, stream>>>(attnb, wo_t, ob, 2048, 1024, 1024);
  addnorm_kernel<<<2048, 256, 0, stream>>>(hidden, ob, x1f, x1b);
  gemm_bt<<<dim3(5632 / 128, 2048 / 128), 256, 0, stream>>>(x1b, wgu_t, gub, 2048, 5632, 1024);
  swiglu_kernel<<<2048, 256, 0, stream>>>(gub, hb);
  gemm_bt64<<<dim3(1024 / 128, 2048 / 64), 256, 0, stream>>>(hb, wd_t, mlpb, 2048, 1024, 2816);
  addnorm_kernel<<<2048, 256, 0, stream>>>(x1f, mlpb, out, nullptr);
}